// Round 2
// baseline (545.428 us; speedup 1.0000x reference)
//
#include <hip/hip_runtime.h>

// Deformable 2x bilinear upsample — LDS-staged gather, reg-staged writes.
// input:  (B=8, C=128, H=128, W=128) fp32
// offset_x/offset_y: (B, 1, Ho=256, Wo=256) fp32
// out:    (B, C, Ho, Wo) fp32
//
// v0 (450 us harness): per-thread scattered gathers -> VMEM request-rate bound
//   (32 cy/instr, 24% HBM peak, 9% VALU).
// v1: global_load_lds staging -> FAILED correctness (suspect: per-wave LDS base
//   uniformity/M0 pairing across 4 unrolled calls).
// v2 (this): identical window/weight logic, but staging is explicit
//   global_load_dwordx4 -> registers -> ds_write_b128 (per-lane, no uniformity
//   requirement), with T14 async-split: loads for stage s+1 issued right after
//   the barrier so HBM latency hides under stage-s compute.

constexpr int B  = 8;
constexpr int C  = 128;
constexpr int H  = 128;
constexpr int W  = 128;
constexpr int KH = 2;
constexpr int KW = 2;
constexpr int Ho = H * KH;     // 256
constexpr int Wo = W * KW;     // 256
constexpr int HW = H * W;      // 16384
constexpr int CG  = 4;         // channel groups (grid.z)
constexpr int CPG = C / CG;    // 32 channels per block
constexpr int NC  = 2;         // channels staged per iteration
constexpr int NSTAGE = CPG / NC;   // 16
constexpr int WR = 16;         // staged window rows
constexpr int WWORDS = WR * W; // 2048 words per channel window

__global__ __launch_bounds__(256, 6) void deform_upsample_kernel(
    const float* __restrict__ in,
    const float* __restrict__ offx,
    const float* __restrict__ offy,
    float* __restrict__ out)
{
    __shared__ float smem[NC * WWORDS];   // 16 KiB

    const int t    = threadIdx.x;
    const int lane = t & 63;
    const int wv   = t >> 6;              // wave 0..3, one output row each
    const int wo4  = lane * 4;
    const int ho   = blockIdx.x * 4 + wv;
    const int b    = blockIdx.y;
    const int c0   = blockIdx.z * CPG;

    const int h0  = blockIdx.x * 2;                  // input row of block's first output row
    const int iy0 = min(max(h0 - 6, 0), H - WR);     // window start (always fully in-range)

    // ---- staging geometry: 4 segments/wave x (64 lanes x 4 words) = 4096 words ----
    int segw[4];           // per-lane LDS word offset
    const float* gsrc[4];  // per-lane global source
#pragma unroll
    for (int q = 0; q < 4; ++q) {
        const int fw  = ((q * 4 + wv) << 8) + (lane << 2);   // flat word in [0,4096)
        const int chs = fw >> 11;                            // staged channel 0/1
        const int rem = fw & (WWORDS - 1);
        const int rr  = rem >> 7;                            // window row 0..15
        const int xx  = rem & (W - 1);                       // col, multiple of 4
        segw[q] = fw;
        gsrc[q] = in + (size_t)(b * C + c0 + chs) * HW + (iy0 + rr) * W + xx;
    }

    // issue stage-0 loads ASAP (latency overlaps with coordinate math below)
    float4 stg[4];
#pragma unroll
    for (int q = 0; q < 4; ++q)
        stg[q] = *reinterpret_cast<const float4*>(gsrc[q]);

    // ---- per-position coordinate precompute (channel-invariant) ----
    const int sbase = (b * Ho + ho) * Wo + wo4;
    const float4 ox4 = *reinterpret_cast<const float4*>(offx + sbase);
    const float4 oy4 = *reinterpret_cast<const float4*>(offy + sbase);
    const float oxv[4] = {ox4.x, ox4.y, ox4.z, ox4.w};
    const float oyv[4] = {oy4.x, oy4.y, oy4.z, oy4.w};

    float wt0[4], wt1[4], wb0[4], wb1[4];  // weights for (top,bot) x (word0,word1)
    int   otv[4], obv[4];                  // LDS word offsets of top/bot pairs
    unsigned fbmask = 0;                   // positions needing global fallback

    const float base_y = (float)ho * 0.5f;
#pragma unroll
    for (int j = 0; j < 4; ++j) {
        const float y = base_y + oyv[j];
        const float x = (float)(wo4 + j) * 0.5f + oxv[j];
        const float y0f = floorf(y), x0f = floorf(x);
        const float wy = y - y0f, wx = x - x0f;
        const int y0 = (int)y0f, x0 = (int)x0f;
        const int y1 = y0 + 1, x1 = x0 + 1;
        const bool vy0 = ((unsigned)y0 < (unsigned)H);
        const bool vy1 = ((unsigned)y1 < (unsigned)H);
        const bool vx0 = ((unsigned)x0 < (unsigned)W);
        const bool vx1 = ((unsigned)x1 < (unsigned)W);
        const int yc0 = min(max(y0, 0), H - 1);
        const int yc1 = min(max(y1, 0), H - 1);
        const int xc0 = min(max(x0, 0), W - 1);
        const int xc1 = min(max(x1, 0), W - 1);
        const int xb  = min(max(x0, 0), W - 2);   // pair base; xc0,xc1 in {xb, xb+1}

        const float omwy = 1.0f - wy, omwx = 1.0f - wx;
        const float w00 = (vy0 && vx0) ? (omwy * omwx) : 0.0f;
        const float w01 = (vy0 && vx1) ? (omwy * wx)   : 0.0f;
        const float w10 = (vy1 && vx0) ? (wy * omwx)   : 0.0f;
        const float w11 = (vy1 && vx1) ? (wy * wx)     : 0.0f;

        // fold x-clamp into pair weights: corner value = word0 if xc==xb else word1
        wt0[j] = (xc0 == xb ? w00 : 0.0f) + (xc1 == xb ? w01 : 0.0f);
        wt1[j] = (xc0 == xb ? 0.0f : w00) + (xc1 == xb ? 0.0f : w01);
        wb0[j] = (xc0 == xb ? w10 : 0.0f) + (xc1 == xb ? w11 : 0.0f);
        wb1[j] = (xc0 == xb ? 0.0f : w10) + (xc1 == xb ? 0.0f : w11);

        const int yr0 = yc0 - iy0, yr1 = yc1 - iy0;
        fbmask |= (unsigned)((yr0 < 0) | (yr1 > WR - 1)) << j;
        const int yr0c = min(max(yr0, 0), WR - 1);
        const int yr1c = min(max(yr1, 0), WR - 1);
        otv[j] = yr0c * W + xb;
        obv[j] = yr1c * W + xb;
    }

    const float* ipfb = in + (size_t)(b * C + c0) * HW;
    float* op = out + ((size_t)(b * C + c0) * Ho + ho) * Wo + wo4;

    for (int s = 0; s < NSTAGE; ++s) {
        if (s > 0)
            __syncthreads();   // all waves done READING stage s-1 before overwrite

        // write staged registers -> LDS (per-lane ds_write_b128, contiguous per wave)
#pragma unroll
        for (int q = 0; q < 4; ++q)
            *reinterpret_cast<float4*>(smem + segw[q]) = stg[q];

        __syncthreads();       // stage-s window resident for all waves

        // T14: issue next stage's global loads now; latency hides under compute
        if (s + 1 < NSTAGE) {
#pragma unroll
            for (int q = 0; q < 4; ++q) {
                gsrc[q] += NC * HW;
                stg[q] = *reinterpret_cast<const float4*>(gsrc[q]);
            }
        }

#pragma unroll
        for (int c = 0; c < NC; ++c) {
            const float* lw = smem + c * WWORDS;
            float r[4];
#pragma unroll
            for (int j = 0; j < 4; ++j) {
                const float t0v = lw[otv[j]];
                const float t1v = lw[otv[j] + 1];   // merges to ds_read2_b32
                const float b0v = lw[obv[j]];
                const float b1v = lw[obv[j] + 1];
                float acc = wt0[j] * t0v;
                acc = fmaf(wt1[j], t1v, acc);
                acc = fmaf(wb0[j], b0v, acc);
                acc = fmaf(wb1[j], b1v, acc);
                r[j] = acc;
            }
            if (__builtin_expect(fbmask != 0u, 0)) {   // ~never taken for N(0,1) offsets
                const float* ipc = ipfb + (size_t)(s * NC + c) * HW;
#pragma unroll
                for (int j = 0; j < 4; ++j) {
                    if ((fbmask >> j) & 1u) {
                        const float y = base_y + oyv[j];
                        const int y0 = (int)floorf(y);
                        const int yc0 = min(max(y0, 0), H - 1);
                        const int yc1 = min(max(y0 + 1, 0), H - 1);
                        const float t0v = ipc[yc0 * W + (otv[j] & (W - 1))];
                        const float t1v = ipc[yc0 * W + (otv[j] & (W - 1)) + 1];
                        const float b0v = ipc[yc1 * W + (obv[j] & (W - 1))];
                        const float b1v = ipc[yc1 * W + (obv[j] & (W - 1)) + 1];
                        float acc = wt0[j] * t0v;
                        acc = fmaf(wt1[j], t1v, acc);
                        acc = fmaf(wb0[j], b0v, acc);
                        acc = fmaf(wb1[j], b1v, acc);
                        r[j] = acc;
                    }
                }
            }
            *reinterpret_cast<float4*>(op + (size_t)(s * NC + c) * (size_t)(Ho * Wo)) =
                make_float4(r[0], r[1], r[2], r[3]);
        }
    }
}

extern "C" void kernel_launch(void* const* d_in, const int* in_sizes, int n_in,
                              void* d_out, int out_size, void* d_ws, size_t ws_size,
                              hipStream_t stream) {
    const float* in   = (const float*)d_in[0];
    const float* offx = (const float*)d_in[1];
    const float* offy = (const float*)d_in[2];
    float* out = (float*)d_out;

    dim3 grid(Ho / 4, B, CG);   // 64 x 8 x 4 = 2048 blocks = 8 blocks/CU
    dim3 block(256);
    deform_upsample_kernel<<<grid, block, 0, stream>>>(in, offx, offy, out);
}

// Round 3
// 321.498 us; speedup vs baseline: 1.6965x; 1.6965x over previous
//
#include <hip/hip_runtime.h>

// Deformable 2x bilinear upsample — v3: traffic-minimized LDS staging.
// input:  (B=8, C=128, H=128, W=128) fp32
// offset_x/offset_y: (B, 1, Ho=256, Wo=256) fp32
// out:    (B, C, Ho, Wo) fp32
//
// v0: scattered gathers, VMEM request-rate bound (218 us, 1.9 TB/s).
// v2: LDS-staged, correct, but TCC-traffic bound (311 us): 8x staging
//     amplification (512 MiB) + 2.8x write amplification from L2 thrash.
// v3: (a) 1024-thr blocks, 16 output rows, window 16 advance 8 -> staged
//     reads 512->128 MiB; (b) XCD-chunked remap: one (b,cg) slice (2 MiB,
//     fits per-XCD L2) stays on one XCD so window overlap hits local L2;
//     (c) nontemporal output stores -> no dirty-line thrash, WRITE ~256 MiB.

constexpr int B  = 8;
constexpr int C  = 128;
constexpr int H  = 128;
constexpr int W  = 128;
constexpr int KH = 2;
constexpr int KW = 2;
constexpr int Ho = H * KH;     // 256
constexpr int Wo = W * KW;     // 256
constexpr int HW = H * W;      // 16384
constexpr int CG  = 4;         // channel groups
constexpr int CPG = C / CG;    // 32 channels per block
constexpr int NC  = 2;         // channels staged per stage
constexpr int NSTAGE = CPG / NC;   // 16
constexpr int TR = 16;         // output rows per block
constexpr int ADV = TR / 2;    // 8 input rows advanced per x-tile
constexpr int WR = 16;         // staged window rows
constexpr int WWORDS = WR * W; // 2048 words per channel window
constexpr int NXT = Ho / TR;   // 16 x-tiles

using f32x4 = __attribute__((ext_vector_type(4))) float;

__global__ __launch_bounds__(1024, 8) void deform_upsample_kernel(
    const float* __restrict__ in,
    const float* __restrict__ offx,
    const float* __restrict__ offy,
    float* __restrict__ out)
{
    __shared__ float smem[2][NC * WWORDS];   // 2 x 16 KiB (double buffer)

    // ---- XCD-chunked remap: hardware round-robins wgid%8 across XCDs.
    // Give XCD x the 4 slices (b,cg) = [4x, 4x+4); within a slice, bx walks
    // the 16 row-tiles whose windows overlap -> overlap hits that XCD's L2.
    const int wgid  = blockIdx.x;            // 0..511
    const int xcd   = wgid & 7;
    const int k     = wgid >> 3;             // 0..63
    const int bx    = k & (NXT - 1);         // 0..15
    const int slice = xcd * 4 + (k >> 4);    // 0..31
    const int bz    = slice & (CG - 1);
    const int b     = slice >> 2;

    const int t    = threadIdx.x;
    const int lane = t & 63;
    const int wv   = t >> 6;                 // wave 0..15, one output row each
    const int wo4  = lane * 4;
    const int ho   = bx * TR + wv;
    const int c0   = bz * CPG;

    const int iy0 = min(max(bx * ADV - 4, 0), H - WR);   // window start

    // ---- staging: thread t covers words [4t, 4t+4) of the 4096-word
    // (2-channel) window pack; window is contiguous in global memory.
    const int fw  = t * 4;
    const int chs = fw >> 11;                // staged channel 0/1
    const int rem = fw & (WWORDS - 1);
    const float* gsrc = in + (size_t)(b * C + c0 + chs) * HW + iy0 * W + rem;

    float4 stg = *reinterpret_cast<const float4*>(gsrc);   // stage 0 (issued ASAP)

    // ---- per-position coordinate precompute (channel-invariant) ----
    const int sbase = (b * Ho + ho) * Wo + wo4;
    const float4 ox4 = *reinterpret_cast<const float4*>(offx + sbase);
    const float4 oy4 = *reinterpret_cast<const float4*>(offy + sbase);
    const float oxv[4] = {ox4.x, ox4.y, ox4.z, ox4.w};
    const float oyv[4] = {oy4.x, oy4.y, oy4.z, oy4.w};

    float wt0[4], wt1[4], wb0[4], wb1[4];  // (top,bot) x (word0,word1) weights
    int   otv[4], obv[4];                  // LDS word offsets of top/bot pairs
    unsigned fbmask = 0;                   // positions needing global fallback

    const float base_y = (float)ho * 0.5f;
#pragma unroll
    for (int j = 0; j < 4; ++j) {
        const float y = base_y + oyv[j];
        const float x = (float)(wo4 + j) * 0.5f + oxv[j];
        const float y0f = floorf(y), x0f = floorf(x);
        const float wy = y - y0f, wx = x - x0f;
        const int y0 = (int)y0f, x0 = (int)x0f;
        const int y1 = y0 + 1, x1 = x0 + 1;
        const bool vy0 = ((unsigned)y0 < (unsigned)H);
        const bool vy1 = ((unsigned)y1 < (unsigned)H);
        const bool vx0 = ((unsigned)x0 < (unsigned)W);
        const bool vx1 = ((unsigned)x1 < (unsigned)W);
        const int yc0 = min(max(y0, 0), H - 1);
        const int yc1 = min(max(y1, 0), H - 1);
        const int xc0 = min(max(x0, 0), W - 1);
        const int xc1 = min(max(x1, 0), W - 1);
        const int xb  = min(max(x0, 0), W - 2);   // pair base; xc0,xc1 in {xb,xb+1}

        const float omwy = 1.0f - wy, omwx = 1.0f - wx;
        const float w00 = (vy0 && vx0) ? (omwy * omwx) : 0.0f;
        const float w01 = (vy0 && vx1) ? (omwy * wx)   : 0.0f;
        const float w10 = (vy1 && vx0) ? (wy * omwx)   : 0.0f;
        const float w11 = (vy1 && vx1) ? (wy * wx)     : 0.0f;

        // fold x-clamp into pair weights: corner value = word0 if xc==xb else word1
        wt0[j] = (xc0 == xb ? w00 : 0.0f) + (xc1 == xb ? w01 : 0.0f);
        wt1[j] = (xc0 == xb ? 0.0f : w00) + (xc1 == xb ? 0.0f : w01);
        wb0[j] = (xc0 == xb ? w10 : 0.0f) + (xc1 == xb ? w11 : 0.0f);
        wb1[j] = (xc0 == xb ? 0.0f : w10) + (xc1 == xb ? 0.0f : w11);

        const int yr0 = yc0 - iy0, yr1 = yc1 - iy0;
        fbmask |= (unsigned)((yr0 < 0) | (yr1 > WR - 1)) << j;
        const int yr0c = min(max(yr0, 0), WR - 1);
        const int yr1c = min(max(yr1, 0), WR - 1);
        otv[j] = yr0c * W + xb;
        obv[j] = yr1c * W + xb;
    }

    // prologue: write stage 0, issue stage 1 loads, publish buffer
    *reinterpret_cast<float4*>(&smem[0][fw]) = stg;
    gsrc += NC * HW;
    stg = *reinterpret_cast<const float4*>(gsrc);   // stage 1 in flight
    __syncthreads();

    const float* ipfb = in + (size_t)(b * C + c0) * HW;
    float* op = out + ((size_t)(b * C + c0) * Ho + ho) * Wo + wo4;

    int cur = 0;
    for (int s = 0; s < NSTAGE; ++s) {
#pragma unroll
        for (int c = 0; c < NC; ++c) {
            const float* lw = &smem[cur][c * WWORDS];
            float r[4];
#pragma unroll
            for (int j = 0; j < 4; ++j) {
                const float t0v = lw[otv[j]];
                const float t1v = lw[otv[j] + 1];   // merges to ds_read2_b32
                const float b0v = lw[obv[j]];
                const float b1v = lw[obv[j] + 1];
                float acc = wt0[j] * t0v;
                acc = fmaf(wt1[j], t1v, acc);
                acc = fmaf(wb0[j], b0v, acc);
                acc = fmaf(wb1[j], b1v, acc);
                r[j] = acc;
            }
            if (__builtin_expect(fbmask != 0u, 0)) {   // ~1e-4/position
                const float* ipc = ipfb + (size_t)(s * NC + c) * HW;
#pragma unroll
                for (int j = 0; j < 4; ++j) {
                    if ((fbmask >> j) & 1u) {
                        const float y = base_y + oyv[j];
                        const int y0 = (int)floorf(y);
                        const int yc0 = min(max(y0, 0), H - 1);
                        const int yc1 = min(max(y0 + 1, 0), H - 1);
                        const int xb  = otv[j] & (W - 1);
                        const float t0v = ipc[yc0 * W + xb];
                        const float t1v = ipc[yc0 * W + xb + 1];
                        const float b0v = ipc[yc1 * W + xb];
                        const float b1v = ipc[yc1 * W + xb + 1];
                        float acc = wt0[j] * t0v;
                        acc = fmaf(wt1[j], t1v, acc);
                        acc = fmaf(wb0[j], b0v, acc);
                        acc = fmaf(wb1[j], b1v, acc);
                        r[j] = acc;
                    }
                }
            }
            // streaming store: output is never re-read; keep it out of L2
            f32x4 rv = {r[0], r[1], r[2], r[3]};
            __builtin_nontemporal_store(
                rv, reinterpret_cast<f32x4*>(op + (size_t)(s * NC + c) * (size_t)(Ho * Wo)));
        }
        __syncthreads();   // all waves done reading smem[cur] (and cur^1 long ago)
        if (s + 1 < NSTAGE) {
            *reinterpret_cast<float4*>(&smem[cur ^ 1][fw]) = stg;   // publish s+1
            if (s + 2 < NSTAGE) {
                gsrc += NC * HW;
                stg = *reinterpret_cast<const float4*>(gsrc);       // s+2 in flight
            }
            __syncthreads();   // s+1 visible before anyone reads it
            cur ^= 1;
        }
    }
}

extern "C" void kernel_launch(void* const* d_in, const int* in_sizes, int n_in,
                              void* d_out, int out_size, void* d_ws, size_t ws_size,
                              hipStream_t stream) {
    const float* in   = (const float*)d_in[0];
    const float* offx = (const float*)d_in[1];
    const float* offy = (const float*)d_in[2];
    float* out = (float*)d_out;

    dim3 grid(NXT * B * CG);   // 512 blocks = 2 blocks/CU (1024 thr each)
    dim3 block(1024);
    deform_upsample_kernel<<<grid, block, 0, stream>>>(in, offx, offy, out);
}